// Round 1
// baseline (158.460 us; speedup 1.0000x reference)
//
#include <hip/hip_runtime.h>
#include <math.h>

#define B 8
#define C 512
#define L 8192
#define CS 16
#define N 512      // L/CS chunk steps
#define C8 64      // C/8 bottleneck dim

// ---------------------------------------------------------------------------
// Kernel 1: chunked average pooling.  x [B,C,L] -> pool [B,N,C]
// 4 threads per chunk, each loads one float4; read address is x4[id] (fully
// coalesced). Quad shuffle-reduce, lane 0 writes.
// ---------------------------------------------------------------------------
__global__ __launch_bounds__(256) void pool_k(const float* __restrict__ x,
                                              float* __restrict__ pool) {
    const int id = blockIdx.x * 256 + threadIdx.x;      // B*C*N*4 threads
    const int q = id & 3;
    const int chunk = id >> 2;                          // (b*C + c)*N + n
    const int n = chunk & (N - 1);
    const int bc = chunk >> 9;                          // b*C + c
    const int c = bc & (C - 1);
    const int b = bc >> 9;

    const float4 v = reinterpret_cast<const float4*>(x)[id];
    float s = v.x + v.y + v.z + v.w;
    s += __shfl_down(s, 1, 4);
    s += __shfl_down(s, 2, 4);
    if (q == 0) {
        pool[((size_t)b * N + n) * C + c] = s * (1.0f / 16.0f);
    }
}

// ---------------------------------------------------------------------------
// Kernel 2: causal EMA over chunk steps, in-place on pool ([B,N,C]).
// One thread per (b,c). At each step n, threads (consecutive c) read/write
// contiguous addresses -> coalesced.
// ---------------------------------------------------------------------------
__global__ __launch_bounds__(256) void ema_k(const float* __restrict__ gamma,
                                             float* __restrict__ pool) {
    const int id = blockIdx.x * 256 + threadIdx.x;      // B*C threads
    const int c = id & (C - 1);
    const int b = id >> 9;
    const float g = gamma[c];
    const float omg = 1.0f - g;
    float* p = pool + (size_t)b * N * C + c;
    float y = 0.0f;
#pragma unroll 8
    for (int n = 0; n < N; ++n) {
        const float xv = p[(size_t)n * C];
        y = fmaf(g, y, omg * xv);
        p[(size_t)n * C] = y;
    }
}

// ---------------------------------------------------------------------------
// Kernel 3: transpose the two 1x1-conv weights so SE matvec reads are
// lane-contiguous.  w1 [C8][C] -> w1t [C][C8];  w2 [C][C8] -> w2t [C8][C].
// ---------------------------------------------------------------------------
__global__ __launch_bounds__(256) void transpose_k(const float* __restrict__ w1,
                                                   const float* __restrict__ w2,
                                                   float* __restrict__ w1t,
                                                   float* __restrict__ w2t) {
    const int id = blockIdx.x * 256 + threadIdx.x;      // C8*C threads
    {   // w1
        const int o = id >> 9;        // / C
        const int k = id & (C - 1);
        w1t[k * C8 + o] = w1[id];
    }
    {   // w2
        const int c = id >> 6;        // / C8
        const int k = id & (C8 - 1);
        w2t[k * C + c] = w2[id];
    }
}

// ---------------------------------------------------------------------------
// Kernel 4: SE bottleneck + sigmoid.  e [B,N,C] -> gate [B,N,C].
// One block handles NT=4 consecutive chunk steps of one batch.
// ---------------------------------------------------------------------------
#define NT 4
__global__ __launch_bounds__(256) void se_k(const float* __restrict__ e,
                                            const float* __restrict__ w1t,
                                            const float* __restrict__ b1,
                                            const float* __restrict__ w2t,
                                            const float* __restrict__ b2,
                                            float* __restrict__ gate) {
    __shared__ float e_s[NT * C];     // 8 KB
    __shared__ float h_s[NT][C8];     // 1 KB

    const int t = threadIdx.x;
    const int blk = blockIdx.x;                  // B*N/NT blocks
    const int b = blk / (N / NT);
    const int n0 = (blk % (N / NT)) * NT;
    const float* ebase = e + ((size_t)b * N + n0) * C;

#pragma unroll
    for (int i = 0; i < NT * C / 256; ++i)
        e_s[i * 256 + t] = ebase[i * 256 + t];
    __syncthreads();

    // h[j][o] = relu(b1[o] + sum_k w1[o,k] * e[j,k])
    const int o = t & (C8 - 1);
    const int j = t >> 6;
    float acc = b1[o];
#pragma unroll 8
    for (int k = 0; k < C; ++k)
        acc = fmaf(w1t[k * C8 + o], e_s[j * C + k], acc);
    h_s[j][o] = fmaxf(acc, 0.0f);
    __syncthreads();

    // gate[j][c] = sigmoid(b2[c] + sum_k w2[c,k] * h[j][k])
    float* gbase = gate + ((size_t)b * N + n0) * C;
#pragma unroll
    for (int r = 0; r < NT * C / 256; ++r) {
        const int idx = r * 256 + t;             // = jj*C + c
        const int c = idx & (C - 1);
        const int jj = idx >> 9;
        float a = b2[c];
#pragma unroll
        for (int k = 0; k < C8; ++k)
            a = fmaf(w2t[k * C + c], h_s[jj][k], a);
        gbase[idx] = 1.0f / (1.0f + __expf(-a));
    }
}

// ---------------------------------------------------------------------------
// Kernel 5: apply gate to residual.  out[b,c,l] = gate[b, l/16, c] * x[b,c,l]
// float4 per thread; a float4 never crosses a chunk boundary (16 % 4 == 0).
// ---------------------------------------------------------------------------
__global__ __launch_bounds__(256) void apply_k(const float* __restrict__ x,
                                               const float* __restrict__ gate,
                                               float* __restrict__ out) {
    const size_t id = (size_t)blockIdx.x * 256 + threadIdx.x;   // float4 index
    const int per_row = L / 4;                   // 2048 float4 per (b,c) row
    const int bc = (int)(id / per_row);
    const int wi = (int)(id % per_row);
    const int n = wi >> 2;                       // (wi*4)/16
    const int c = bc & (C - 1);
    const int b = bc >> 9;

    const float g = gate[((size_t)b * N + n) * C + c];
    float4 v = reinterpret_cast<const float4*>(x)[id];
    v.x *= g; v.y *= g; v.z *= g; v.w *= g;
    reinterpret_cast<float4*>(out)[id] = v;
}

// ---------------------------------------------------------------------------
extern "C" void kernel_launch(void* const* d_in, const int* in_sizes, int n_in,
                              void* d_out, int out_size, void* d_ws, size_t ws_size,
                              hipStream_t stream) {
    const float* x     = (const float*)d_in[0];
    const float* gamma = (const float*)d_in[1];
    const float* w1    = (const float*)d_in[2];
    const float* b1    = (const float*)d_in[3];
    const float* w2    = (const float*)d_in[4];
    const float* b2    = (const float*)d_in[5];
    float* out = (float*)d_out;

    char* ws = (char*)d_ws;
    float* pool = (float*)(ws);                                  // B*N*C f32 = 8 MB
    float* gate = (float*)(ws + (size_t)B * N * C * 4);          // 8 MB
    float* w1t  = (float*)(ws + (size_t)2 * B * N * C * 4);      // 128 KB
    float* w2t  = (float*)(ws + (size_t)2 * B * N * C * 4 + (size_t)C8 * C * 4);

    // weights transpose (tiny)
    transpose_k<<<(C8 * C) / 256, 256, 0, stream>>>(w1, w2, w1t, w2t);
    // chunk pooling
    pool_k<<<(B * C * N * 4) / 256, 256, 0, stream>>>(x, pool);
    // causal EMA (in-place on pool -> e)
    ema_k<<<(B * C) / 256, 256, 0, stream>>>(gamma, pool);
    // SE bottleneck -> gate
    se_k<<<(B * N) / NT, 256, 0, stream>>>(pool, w1t, b1, w2t, b2, gate);
    // apply gate
    apply_k<<<(B * C * L / 4) / 256, 256, 0, stream>>>(x, gate, out);
}